// Round 12
// baseline (71.443 us; speedup 1.0000x reference)
//
#include <hip/hip_runtime.h>
#include <hip/hip_bf16.h>

using f16   = _Float16;
using f16x4 = __attribute__((ext_vector_type(4))) _Float16;
using f16x8 = __attribute__((ext_vector_type(8))) _Float16;
using f32x4 = __attribute__((ext_vector_type(4))) float;

// ---------------- prep: pack node weights as f16 in MFMA-fragment layouts ----------------
// wf layout: [0,4992)    WnT [48][104], k>=90 zeroed
//            [4992,8576) P   [64][56],  j>=48 zeroed
//            [8576,12032) PnT [48][72], p>=64 zeroed
// q[64] = ||P_p||^2 (f32)
__global__ __launch_bounds__(256) void prep_kernel(
    const float* __restrict__ Wn, const float* __restrict__ Pn,
    f16* __restrict__ wf, float* __restrict__ q)
{
  int i = blockIdx.x * 256 + threadIdx.x;
  if (i < 4992) {
    int n = i / 104, k = i - n * 104;
    wf[i] = (k < 90) ? (f16)Wn[k * 48 + n] : (f16)0.f;
  } else if (i < 8576) {
    int j = i - 4992; int p = j / 56, c = j - p * 56;
    wf[i] = (c < 48) ? (f16)Pn[p * 48 + c] : (f16)0.f;
  } else if (i < 12032) {
    int j = i - 8576; int r = j / 72, p = j - r * 72;
    wf[i] = (p < 64) ? (f16)Pn[p * 48 + r] : (f16)0.f;
  } else if (i < 12096) {
    int p = i - 12032;
    float s = 0.f;
    for (int j = 0; j < 48; ++j) { float v = Pn[p * 48 + j]; s = fmaf(v, v, s); }
    q[p] = s;
  }
}

// ---------------- Wc1 [8736][256] f32 -> Wc1T [256][8736] f16 ----------------
__global__ __launch_bounds__(256) void wc1t_kernel(
    const float* __restrict__ Wc1, f16* __restrict__ Wc1T)
{
  __shared__ f16 sT[32 * 36];
  const int tid = threadIdx.x;
  const int kt = blockIdx.x, ct = blockIdx.y;
  const int c = tid & 31, r4 = (tid >> 5) * 4;
  #pragma unroll
  for (int i = 0; i < 4; ++i) {
    int r = r4 + i;
    sT[c * 36 + r] = (f16)Wc1[(size_t)(kt * 32 + r) * 256 + ct * 32 + c];
  }
  __syncthreads();
  #pragma unroll
  for (int i = 0; i < 4; ++i) {
    int r = r4 + i;
    Wc1T[(size_t)(ct * 32 + r) * 8736 + kt * 32 + c] = sT[r * 36 + c];
  }
}

// ---------------- Kernel A: node embed + soft-proto + mean, wave-per-strip ----------------
// one block (384 thr, 6 waves) per (sample, branch); wave w owns rows [16w,16w+16).
// NO inter-wave barriers until the final mean: each wave runs embed->scores->softmax->w@P
// on its strip using wave-private LDS scratch for the two layout transposes.
__global__ __launch_bounds__(384) void node_kernel(
    const float* __restrict__ fcn, const float* __restrict__ scn,
    const float* __restrict__ bn, const f16* __restrict__ wf,
    const float* __restrict__ qg,
    f16* __restrict__ R, float* __restrict__ nmmean)
{
  __shared__ __align__(16) f16 sS[6][1152];   // per-wave scratch: nodes [16][56] then w [16][72]
  __shared__ float sQ[64];
  __shared__ float sCol[6][3][16];

  const f16* Pw   = wf + 4992;     // [64][56]
  const f16* PnTw = wf + 8576;     // [48][72]

  const int tid = threadIdx.x;
  const int lane = tid & 63, wv = tid >> 6;      // wv = strip 0..5
  const int l15 = lane & 15, lg = lane >> 4;
  const int b = blockIdx.x, br = blockIdx.y;
  const float* x = (br ? scn : fcn) + (size_t)b * 8100;
  f16* scr = sS[wv];

  if (tid < 64) sQ[tid] = qg[tid];   // safe: consumed after first syncthreads-free phase by all waves? wave0 writes, all read.
  // NOTE: sQ is written by wave 0 only; other waves read it in ph2. Without a barrier this
  // would race -- so instead every wave loads q redundantly into registers (below).

  // ---- ph1: nodes(strip) = x @ Wn + bn ; A regs from global, B from wf ----
  const int row = wv * 16 + l15;
  const float* xrow = x + row * 90;
  f16x8 a[3];
  #pragma unroll
  for (int kt = 0; kt < 3; ++kt) {
    const int k0 = kt * 32 + lg * 8;
    f16x8 h;
    #pragma unroll
    for (int e = 0; e < 8; ++e) h[e] = (f16)0.f;
    if (row < 90) {
      const float* src = xrow + k0;
      if (k0 < 88) {
        float2 u0 = *(const float2*)(src + 0);
        float2 u1 = *(const float2*)(src + 2);
        float2 u2 = *(const float2*)(src + 4);
        float2 u3 = *(const float2*)(src + 6);
        h[0] = (f16)u0.x; h[1] = (f16)u0.y; h[2] = (f16)u1.x; h[3] = (f16)u1.y;
        h[4] = (f16)u2.x; h[5] = (f16)u2.y; h[6] = (f16)u3.x; h[7] = (f16)u3.y;
      } else {                      // k0 == 88: cols 88,89 real, 90..95 pad
        float2 u0 = *(const float2*)src;
        h[0] = (f16)u0.x; h[1] = (f16)u0.y;
      }
    }
    a[kt] = h;
  }
  #pragma unroll
  for (int nt = 0; nt < 3; ++nt) {
    f32x4 acc = {0.f, 0.f, 0.f, 0.f};
    #pragma unroll
    for (int kt = 0; kt < 3; ++kt) {
      f16x8 bb = *(const f16x8*)&wf[(nt * 16 + l15) * 104 + kt * 32 + lg * 8];
      acc = __builtin_amdgcn_mfma_f32_16x16x32_f16(a[kt], bb, acc, 0, 0, 0);
    }
    const float bias = bn[nt * 16 + l15];
    #pragma unroll
    for (int r = 0; r < 4; ++r)
      scr[(lg * 4 + r) * 56 + nt * 16 + l15] = (f16)(acc[r] + bias);  // C-layout store
  }
  asm volatile("s_waitcnt lgkmcnt(0)" ::: "memory");   // same-wave LDS RAW
  __builtin_amdgcn_sched_barrier(0);

  // ---- ph2: scores = 2*(nodes @ P^T) - q ; fused row softmax -> w scratch ----
  const f16x8 a0 = *(const f16x8*)&scr[l15 * 56 + lg * 8];       // A-layout read (transpose)
  const f16x4 a1 = *(const f16x4*)&scr[l15 * 56 + 32 + lg * 4];
  f32x4 acc2[4];
  #pragma unroll
  for (int nt = 0; nt < 4; ++nt) acc2[nt] = (f32x4){0.f, 0.f, 0.f, 0.f};
  #pragma unroll
  for (int nt = 0; nt < 4; ++nt) {
    f16x8 b0 = *(const f16x8*)&Pw[(nt * 16 + l15) * 56 + lg * 8];
    acc2[nt] = __builtin_amdgcn_mfma_f32_16x16x32_f16(a0, b0, acc2[nt], 0, 0, 0);
    f16x4 b1 = *(const f16x4*)&Pw[(nt * 16 + l15) * 56 + 32 + lg * 4];
    acc2[nt] = __builtin_amdgcn_mfma_f32_16x16x16f16(a1, b1, acc2[nt], 0, 0, 0);
  }
  float qv[4];
  #pragma unroll
  for (int nt = 0; nt < 4; ++nt) qv[nt] = qg[nt * 16 + l15];
  #pragma unroll
  for (int r = 0; r < 4; ++r) {
    float s0 = 2.f * acc2[0][r] - qv[0];
    float s1 = 2.f * acc2[1][r] - qv[1];
    float s2 = 2.f * acc2[2][r] - qv[2];
    float s3 = 2.f * acc2[3][r] - qv[3];
    float m = fmaxf(fmaxf(s0, s1), fmaxf(s2, s3));
    m = fmaxf(m, __shfl_xor(m, 1, 64));
    m = fmaxf(m, __shfl_xor(m, 2, 64));
    m = fmaxf(m, __shfl_xor(m, 4, 64));
    m = fmaxf(m, __shfl_xor(m, 8, 64));
    float e0 = __expf(s0 - m), e1 = __expf(s1 - m);
    float e2 = __expf(s2 - m), e3 = __expf(s3 - m);
    float sum = (e0 + e1) + (e2 + e3);
    sum += __shfl_xor(sum, 1, 64);
    sum += __shfl_xor(sum, 2, 64);
    sum += __shfl_xor(sum, 4, 64);
    sum += __shfl_xor(sum, 8, 64);
    const float inv = 1.f / sum;
    const int lr = lg * 4 + r;
    scr[lr * 72 + 0 * 16 + l15] = (f16)(e0 * inv);   // w C-layout (reuses scratch; nodes
    scr[lr * 72 + 1 * 16 + l15] = (f16)(e1 * inv);   //  already consumed into a0/a1)
    scr[lr * 72 + 2 * 16 + l15] = (f16)(e2 * inv);
    scr[lr * 72 + 3 * 16 + l15] = (f16)(e3 * inv);
  }
  asm volatile("s_waitcnt lgkmcnt(0)" ::: "memory");
  __builtin_amdgcn_sched_barrier(0);

  // ---- ph3: nm(strip) = w @ Pn -> R(f16); col-sums in registers ----
  f16* Rrow = R + (size_t)b * 8736 + (size_t)br * 4320;
  const f16x8 wa0 = *(const f16x8*)&scr[l15 * 72 + lg * 8];        // A-layout read
  const f16x8 wa1 = *(const f16x8*)&scr[l15 * 72 + 32 + lg * 8];
  float cs[3] = {0.f, 0.f, 0.f};
  #pragma unroll
  for (int nt = 0; nt < 3; ++nt) {
    f32x4 acc = {0.f, 0.f, 0.f, 0.f};
    f16x8 b0 = *(const f16x8*)&PnTw[(nt * 16 + l15) * 72 + lg * 8];
    acc = __builtin_amdgcn_mfma_f32_16x16x32_f16(wa0, b0, acc, 0, 0, 0);
    f16x8 b1 = *(const f16x8*)&PnTw[(nt * 16 + l15) * 72 + 32 + lg * 8];
    acc = __builtin_amdgcn_mfma_f32_16x16x32_f16(wa1, b1, acc, 0, 0, 0);
    #pragma unroll
    for (int r = 0; r < 4; ++r) {
      const int grow = wv * 16 + lg * 4 + r;
      if (grow < 90) {
        Rrow[grow * 48 + nt * 16 + l15] = (f16)acc[r];
        cs[nt] += acc[r];
      }
    }
  }
  #pragma unroll
  for (int nt = 0; nt < 3; ++nt) {
    cs[nt] += __shfl_xor(cs[nt], 16, 64);
    cs[nt] += __shfl_xor(cs[nt], 32, 64);
  }
  if (lane < 16) {
    sCol[wv][0][lane] = cs[0];
    sCol[wv][1][lane] = cs[1];
    sCol[wv][2][lane] = cs[2];
  }
  __syncthreads();   // the only block-wide barrier
  if (tid < 48) {
    const int nt = tid >> 4, c = tid & 15;
    float s = 0.f;
    #pragma unroll
    for (int w = 0; w < 6; ++w) s += sCol[w][nt][c];
    nmmean[((size_t)br * 1024 + b) * 48 + tid] = s * (1.f / 90.f);
  }
}

// ---------------- Kernel B: graph-level tiny MLPs + soft-protos ----------------
__global__ __launch_bounds__(256) void graph_kernel(
    const float* __restrict__ nmmean,
    const float* __restrict__ Wg, const float* __restrict__ bg,
    const float* __restrict__ Pg,
    const float* __restrict__ Wg1, const float* __restrict__ bg1,
    const float* __restrict__ Wg2, const float* __restrict__ bg2,
    const float* __restrict__ Pc,
    f16* __restrict__ R)
{
  __shared__ float sE[4][64];
  __shared__ float sT[4][64];
  const int tid = threadIdx.x;
  const int wid = tid >> 6, lane = tid & 63;
  const int idx = blockIdx.x * 4 + wid;
  const int br = idx >> 10, b = idx & 1023;
  const float* mrow = nmmean + (size_t)idx * 48;
  f16* Rrow = R + (size_t)b * 8736;

  if (lane < 32) {
    float e = bg[lane];
    #pragma unroll
    for (int k = 0; k < 48; ++k) e = fmaf(mrow[k], Wg[k * 32 + lane], e);
    sE[wid][lane] = e;
  }
  __syncthreads();
  if (lane < 32) {
    float s = 0.f;
    #pragma unroll
    for (int j = 0; j < 32; ++j) { float pv = Pg[lane * 32 + j]; s += pv * (2.f * sE[wid][j] - pv); }
    float m = s;
    for (int d = 16; d >= 1; d >>= 1) m = fmaxf(m, __shfl_xor(m, d, 64));
    float ex = __expf(s - m);
    float sum = ex;
    for (int d = 16; d >= 1; d >>= 1) sum += __shfl_xor(sum, d, 64);
    sT[wid][lane] = ex / sum;
  }
  __syncthreads();
  if (lane < 32) {
    float g = 0.f;
    #pragma unroll
    for (int p = 0; p < 32; ++p) g = fmaf(sT[wid][p], Pg[p * 32 + lane], g);
    Rrow[8640 + br * 32 + lane] = (f16)g;
    sE[wid][lane] = g;
  }
  __syncthreads();
  if (lane < 32) {
    float h = bg1[lane];
    #pragma unroll
    for (int k = 0; k < 32; ++k) h = fmaf(sE[wid][k], Wg1[k * 32 + lane], h);
    sT[wid][lane] = fmaxf(h, 0.f);
  }
  __syncthreads();
  if (lane < 16) {
    float c = bg2[lane];
    #pragma unroll
    for (int k = 0; k < 32; ++k) c = fmaf(sT[wid][k], Wg2[k * 16 + lane], c);
    sE[wid][lane] = c;
  }
  __syncthreads();
  if (lane < 16) {
    float s = 0.f;
    #pragma unroll
    for (int j = 0; j < 16; ++j) { float pv = Pc[lane * 16 + j]; s += pv * (2.f * sE[wid][j] - pv); }
    float m = s;
    for (int d = 8; d >= 1; d >>= 1) m = fmaxf(m, __shfl_xor(m, d, 64));
    float ex = __expf(s - m);
    float sum = ex;
    for (int d = 8; d >= 1; d >>= 1) sum += __shfl_xor(sum, d, 64);
    sT[wid][lane] = ex / sum;
  }
  __syncthreads();
  if (lane < 16) {
    float c = 0.f;
    #pragma unroll
    for (int p = 0; p < 16; ++p) c = fmaf(sT[wid][p], Pc[p * 16 + lane], c);
    Rrow[8704 + br * 16 + lane] = (f16)c;
  }
}

// ---------------- split-K f16-MFMA GEMM with register prefetch ----------------
__global__ __launch_bounds__(256) void gemm1_kernel(
    const f16* __restrict__ R, const f16* __restrict__ Wc1T,
    float* __restrict__ part, int KS)
{
  __shared__ __align__(16) f16 sA[128 * 40];
  __shared__ __align__(16) f16 sB[64 * 40];
  const int tid = threadIdx.x;
  const int lane = tid & 63, wv = tid >> 6;
  const int l15 = lane & 15, lg = lane >> 4;
  const int wm = wv >> 1, wn = wv & 1;
  const int bm = blockIdx.x * 128, bnc = blockIdx.y * 64, z = blockIdx.z;
  const int base = 273 / KS, rem = 273 - base * KS;
  const int t0 = z * base + (z < rem ? z : rem);
  const int nt_ = base + (z < rem ? 1 : 0);
  const int kbeg = t0 * 32, kend = (t0 + nt_) * 32;

  const int ar = tid >> 1, ah = (tid & 1) * 16;
  const int bc = tid >> 2, bh = (tid & 3) * 8;

  f32x4 acc[4][2];
  #pragma unroll
  for (int mt = 0; mt < 4; ++mt)
    #pragma unroll
    for (int nt = 0; nt < 2; ++nt) acc[mt][nt] = (f32x4){0.f, 0.f, 0.f, 0.f};

  // prefetch first tile into registers
  f16x8 v0 = *(const f16x8*)&R[(size_t)(bm + ar) * 8736 + kbeg + ah];
  f16x8 v1 = *(const f16x8*)&R[(size_t)(bm + ar) * 8736 + kbeg + ah + 8];
  f16x8 w0 = *(const f16x8*)&Wc1T[(size_t)(bnc + bc) * 8736 + kbeg + bh];

  for (int kk = kbeg; kk < kend; kk += 32) {
    *(f16x8*)&sA[ar * 40 + ah] = v0;
    *(f16x8*)&sA[ar * 40 + ah + 8] = v1;
    *(f16x8*)&sB[bc * 40 + bh] = w0;
    __syncthreads();
    if (kk + 32 < kend) {   // issue next-tile loads; latency hides under MFMAs
      v0 = *(const f16x8*)&R[(size_t)(bm + ar) * 8736 + kk + 32 + ah];
      v1 = *(const f16x8*)&R[(size_t)(bm + ar) * 8736 + kk + 32 + ah + 8];
      w0 = *(const f16x8*)&Wc1T[(size_t)(bnc + bc) * 8736 + kk + 32 + bh];
    }
    #pragma unroll
    for (int mt = 0; mt < 4; ++mt) {
      f16x8 a = *(const f16x8*)&sA[(wm * 64 + mt * 16 + l15) * 40 + lg * 8];
      #pragma unroll
      for (int nt = 0; nt < 2; ++nt) {
        f16x8 bb = *(const f16x8*)&sB[(wn * 32 + nt * 16 + l15) * 40 + lg * 8];
        acc[mt][nt] = __builtin_amdgcn_mfma_f32_16x16x32_f16(a, bb, acc[mt][nt], 0, 0, 0);
      }
    }
    __syncthreads();
  }
  float* pz = part + (size_t)z * 262144;
  #pragma unroll
  for (int mt = 0; mt < 4; ++mt)
    #pragma unroll
    for (int nt = 0; nt < 2; ++nt)
      #pragma unroll
      for (int r = 0; r < 4; ++r)
        pz[(size_t)(bm + wm * 64 + mt * 16 + lg * 4 + r) * 256 +
           bnc + wn * 32 + nt * 16 + l15] = acc[mt][nt][r];
}

// ---------------- reduce K-partials + relu + [256->3] head ----------------
__global__ __launch_bounds__(256) void head_kernel(
    const float* __restrict__ part, const float* __restrict__ bc1,
    const float* __restrict__ Wc2, const float* __restrict__ bc2,
    float* __restrict__ out, int KS)
{
  __shared__ float red[3][4];
  const int b = blockIdx.x, t = threadIdx.x;
  float s0 = 0.f, s1 = 0.f, s2 = 0.f, s3 = 0.f;   // independent chains
  int z = 0;
  for (; z + 4 <= KS; z += 4) {
    s0 += part[(size_t)(z + 0) * 262144 + (size_t)b * 256 + t];
    s1 += part[(size_t)(z + 1) * 262144 + (size_t)b * 256 + t];
    s2 += part[(size_t)(z + 2) * 262144 + (size_t)b * 256 + t];
    s3 += part[(size_t)(z + 3) * 262144 + (size_t)b * 256 + t];
  }
  for (; z < KS; ++z) s0 += part[(size_t)z * 262144 + (size_t)b * 256 + t];
  float acc = bc1[t] + ((s0 + s1) + (s2 + s3));
  float h = fmaxf(acc, 0.f);
  float p0 = h * Wc2[t * 3 + 0];
  float p1 = h * Wc2[t * 3 + 1];
  float p2 = h * Wc2[t * 3 + 2];
  for (int d = 32; d >= 1; d >>= 1) {
    p0 += __shfl_xor(p0, d, 64);
    p1 += __shfl_xor(p1, d, 64);
    p2 += __shfl_xor(p2, d, 64);
  }
  const int wid = t >> 6, lane = t & 63;
  if (lane == 0) { red[0][wid] = p0; red[1][wid] = p1; red[2][wid] = p2; }
  __syncthreads();
  if (t < 3) {
    out[(size_t)b * 3 + t] = red[t][0] + red[t][1] + red[t][2] + red[t][3] + bc2[t];
  }
}

extern "C" void kernel_launch(void* const* d_in, const int* in_sizes, int n_in,
                              void* d_out, int out_size, void* d_ws, size_t ws_size,
                              hipStream_t stream) {
  const float* fcn     = (const float*)d_in[0];
  const float* scn     = (const float*)d_in[1];
  const float* W_node  = (const float*)d_in[2];
  const float* b_node  = (const float*)d_in[3];
  const float* P_node  = (const float*)d_in[4];
  const float* W_graph = (const float*)d_in[5];
  const float* b_graph = (const float*)d_in[6];
  const float* P_graph = (const float*)d_in[7];
  const float* Wg1     = (const float*)d_in[8];
  const float* bg1     = (const float*)d_in[9];
  const float* Wg2     = (const float*)d_in[10];
  const float* bg2     = (const float*)d_in[11];
  const float* P_cls   = (const float*)d_in[12];
  const float* Wc1     = (const float*)d_in[13];
  const float* bc1     = (const float*)d_in[14];
  const float* Wc2     = (const float*)d_in[15];
  const float* bc2     = (const float*)d_in[16];
  float* out = (float*)d_out;

  char* ws = (char*)d_ws;
  f16*   R16    = (f16*)ws;                        // 17,891,328 B
  f16*   Wc1T   = (f16*)(ws + 17891328);           //  4,472,832 B
  f16*   wf     = (f16*)(ws + 22364160);           //     24,064 B
  float* qbuf   = (float*)(ws + 22388224);         //        256 B
  float* nmmean = (float*)(ws + 22388480);         //    393,216 B
  float* part   = (float*)(ws + 22781696);         // KS * 1,048,576 B

  size_t avail = ws_size > 22781696u ? ws_size - 22781696u : 0;
  int KS = (int)(avail / 1048576u);
  if (KS > 16) KS = 16;
  if (KS < 1) KS = 1;

  prep_kernel<<<48, 256, 0, stream>>>(W_node, P_node, wf, qbuf);
  wc1t_kernel<<<dim3(273, 8), 256, 0, stream>>>(Wc1, Wc1T);
  node_kernel<<<dim3(1024, 2), 384, 0, stream>>>(fcn, scn, b_node, wf, qbuf,
                                                 R16, nmmean);
  graph_kernel<<<512, 256, 0, stream>>>(nmmean, W_graph, b_graph, P_graph,
                                        Wg1, bg1, Wg2, bg2, P_cls, R16);
  gemm1_kernel<<<dim3(8, 4, KS), 256, 0, stream>>>(R16, Wc1T, part, KS);
  head_kernel<<<1024, 256, 0, stream>>>(part, bc1, Wc2, bc2, out, KS);
}

// Round 13
// 67.855 us; speedup vs baseline: 1.0529x; 1.0529x over previous
//
#include <hip/hip_runtime.h>
#include <hip/hip_bf16.h>

using f16   = _Float16;
using f16x4 = __attribute__((ext_vector_type(4))) _Float16;
using f16x8 = __attribute__((ext_vector_type(8))) _Float16;
using f32x4 = __attribute__((ext_vector_type(4))) float;

// ---------------- prep: pack node weights as f16 in MFMA-fragment layouts ----------------
// wf layout: [0,4992)    WnT [48][104], k>=90 zeroed
//            [4992,8576) P   [64][56],  j>=48 zeroed
//            [8576,12032) PnT [48][72], p>=64 zeroed
// q[64] = ||P_p||^2 (f32)
__global__ __launch_bounds__(256) void prep_kernel(
    const float* __restrict__ Wn, const float* __restrict__ Pn,
    f16* __restrict__ wf, float* __restrict__ q)
{
  int i = blockIdx.x * 256 + threadIdx.x;
  if (i < 4992) {
    int n = i / 104, k = i - n * 104;
    wf[i] = (k < 90) ? (f16)Wn[k * 48 + n] : (f16)0.f;
  } else if (i < 8576) {
    int j = i - 4992; int p = j / 56, c = j - p * 56;
    wf[i] = (c < 48) ? (f16)Pn[p * 48 + c] : (f16)0.f;
  } else if (i < 12032) {
    int j = i - 8576; int r = j / 72, p = j - r * 72;
    wf[i] = (p < 64) ? (f16)Pn[p * 48 + r] : (f16)0.f;
  } else if (i < 12096) {
    int p = i - 12032;
    float s = 0.f;
    for (int j = 0; j < 48; ++j) { float v = Pn[p * 48 + j]; s = fmaf(v, v, s); }
    q[p] = s;
  }
}

// ---------------- Wc1 [8736][256] f32 -> Wc1T [256][8736] f16 ----------------
__global__ __launch_bounds__(256) void wc1t_kernel(
    const float* __restrict__ Wc1, f16* __restrict__ Wc1T)
{
  __shared__ f16 sT[32 * 36];
  const int tid = threadIdx.x;
  const int kt = blockIdx.x, ct = blockIdx.y;
  const int c = tid & 31, r4 = (tid >> 5) * 4;
  #pragma unroll
  for (int i = 0; i < 4; ++i) {
    int r = r4 + i;
    sT[c * 36 + r] = (f16)Wc1[(size_t)(kt * 32 + r) * 256 + ct * 32 + c];
  }
  __syncthreads();
  #pragma unroll
  for (int i = 0; i < 4; ++i) {
    int r = r4 + i;
    Wc1T[(size_t)(ct * 32 + r) * 8736 + kt * 32 + c] = sT[r * 36 + c];
  }
}

// ---------------- Kernel A: node embed + soft-proto + mean, wave-per-strip ----------------
// one block (384 thr, 6 waves) per (sample, branch); wave w owns rows [16w,16w+16).
// Weights staged ONCE into LDS (linear copy + 1 barrier) -> all MFMA B-operands are
// ds_reads, no mid-chain global latency. Waves then run barrier-free to the mean.
__global__ __launch_bounds__(384) void node_kernel(
    const float* __restrict__ fcn, const float* __restrict__ scn,
    const float* __restrict__ bn, const f16* __restrict__ wf,
    const float* __restrict__ qg,
    f16* __restrict__ R, float* __restrict__ nmmean)
{
  __shared__ __align__(16) f16 sWt[12032];    // WnT [48][104] | P [64][56] | PnT [48][72]
  __shared__ __align__(16) f16 sS[6][1152];   // per-wave scratch: nodes [16][56] then w [16][72]
  __shared__ float sCol[6][3][16];

  f16* sWnT = sWt;                // [48][104]
  f16* sP   = sWt + 4992;         // [64][56]
  f16* sPnT = sWt + 8576;         // [48][72]

  const int tid = threadIdx.x;
  const int lane = tid & 63, wv = tid >> 6;      // wv = strip 0..5
  const int l15 = lane & 15, lg = lane >> 4;
  const int b = blockIdx.x, br = blockIdx.y;
  const float* x = (br ? scn : fcn) + (size_t)b * 8100;
  f16* scr = sS[wv];

  // ---- stage all weights: linear conflict-free f16x8 copy, one barrier ----
  for (int i = tid; i < 1504; i += 384)
    ((f16x8*)sWt)[i] = ((const f16x8*)wf)[i];
  __syncthreads();

  // ---- ph1: nodes(strip) = x @ Wn + bn ; A regs from global, B from LDS ----
  const int row = wv * 16 + l15;
  const float* xrow = x + row * 90;
  f16x8 a[3];
  #pragma unroll
  for (int kt = 0; kt < 3; ++kt) {
    const int k0 = kt * 32 + lg * 8;
    f16x8 h;
    #pragma unroll
    for (int e = 0; e < 8; ++e) h[e] = (f16)0.f;
    if (row < 90) {
      const float* src = xrow + k0;
      if (k0 < 88) {
        float2 u0 = *(const float2*)(src + 0);
        float2 u1 = *(const float2*)(src + 2);
        float2 u2 = *(const float2*)(src + 4);
        float2 u3 = *(const float2*)(src + 6);
        h[0] = (f16)u0.x; h[1] = (f16)u0.y; h[2] = (f16)u1.x; h[3] = (f16)u1.y;
        h[4] = (f16)u2.x; h[5] = (f16)u2.y; h[6] = (f16)u3.x; h[7] = (f16)u3.y;
      } else {                      // k0 == 88: cols 88,89 real, 90..95 pad
        float2 u0 = *(const float2*)src;
        h[0] = (f16)u0.x; h[1] = (f16)u0.y;
      }
    }
    a[kt] = h;
  }
  #pragma unroll
  for (int nt = 0; nt < 3; ++nt) {
    f32x4 acc = {0.f, 0.f, 0.f, 0.f};
    #pragma unroll
    for (int kt = 0; kt < 3; ++kt) {
      f16x8 bb = *(const f16x8*)&sWnT[(nt * 16 + l15) * 104 + kt * 32 + lg * 8];
      acc = __builtin_amdgcn_mfma_f32_16x16x32_f16(a[kt], bb, acc, 0, 0, 0);
    }
    const float bias = bn[nt * 16 + l15];
    #pragma unroll
    for (int r = 0; r < 4; ++r)
      scr[(lg * 4 + r) * 56 + nt * 16 + l15] = (f16)(acc[r] + bias);  // C-layout store
  }
  asm volatile("s_waitcnt lgkmcnt(0)" ::: "memory");   // same-wave LDS RAW
  __builtin_amdgcn_sched_barrier(0);

  // ---- ph2: scores = 2*(nodes @ P^T) - q ; fused row softmax -> w scratch ----
  const f16x8 a0 = *(const f16x8*)&scr[l15 * 56 + lg * 8];       // A-layout read (transpose)
  const f16x4 a1 = *(const f16x4*)&scr[l15 * 56 + 32 + lg * 4];
  f32x4 acc2[4];
  #pragma unroll
  for (int nt = 0; nt < 4; ++nt) acc2[nt] = (f32x4){0.f, 0.f, 0.f, 0.f};
  #pragma unroll
  for (int nt = 0; nt < 4; ++nt) {
    f16x8 b0 = *(const f16x8*)&sP[(nt * 16 + l15) * 56 + lg * 8];
    acc2[nt] = __builtin_amdgcn_mfma_f32_16x16x32_f16(a0, b0, acc2[nt], 0, 0, 0);
    f16x4 b1 = *(const f16x4*)&sP[(nt * 16 + l15) * 56 + 32 + lg * 4];
    acc2[nt] = __builtin_amdgcn_mfma_f32_16x16x16f16(a1, b1, acc2[nt], 0, 0, 0);
  }
  float qv[4];
  #pragma unroll
  for (int nt = 0; nt < 4; ++nt) qv[nt] = qg[nt * 16 + l15];
  #pragma unroll
  for (int r = 0; r < 4; ++r) {
    float s0 = 2.f * acc2[0][r] - qv[0];
    float s1 = 2.f * acc2[1][r] - qv[1];
    float s2 = 2.f * acc2[2][r] - qv[2];
    float s3 = 2.f * acc2[3][r] - qv[3];
    float m = fmaxf(fmaxf(s0, s1), fmaxf(s2, s3));
    m = fmaxf(m, __shfl_xor(m, 1, 64));
    m = fmaxf(m, __shfl_xor(m, 2, 64));
    m = fmaxf(m, __shfl_xor(m, 4, 64));
    m = fmaxf(m, __shfl_xor(m, 8, 64));
    float e0 = __expf(s0 - m), e1 = __expf(s1 - m);
    float e2 = __expf(s2 - m), e3 = __expf(s3 - m);
    float sum = (e0 + e1) + (e2 + e3);
    sum += __shfl_xor(sum, 1, 64);
    sum += __shfl_xor(sum, 2, 64);
    sum += __shfl_xor(sum, 4, 64);
    sum += __shfl_xor(sum, 8, 64);
    const float inv = 1.f / sum;
    const int lr = lg * 4 + r;
    scr[lr * 72 + 0 * 16 + l15] = (f16)(e0 * inv);   // w C-layout
    scr[lr * 72 + 1 * 16 + l15] = (f16)(e1 * inv);
    scr[lr * 72 + 2 * 16 + l15] = (f16)(e2 * inv);
    scr[lr * 72 + 3 * 16 + l15] = (f16)(e3 * inv);
  }
  asm volatile("s_waitcnt lgkmcnt(0)" ::: "memory");
  __builtin_amdgcn_sched_barrier(0);

  // ---- ph3: nm(strip) = w @ Pn -> R(f16); col-sums in registers ----
  f16* Rrow = R + (size_t)b * 8736 + (size_t)br * 4320;
  const f16x8 wa0 = *(const f16x8*)&scr[l15 * 72 + lg * 8];        // A-layout read
  const f16x8 wa1 = *(const f16x8*)&scr[l15 * 72 + 32 + lg * 8];
  float cs[3] = {0.f, 0.f, 0.f};
  #pragma unroll
  for (int nt = 0; nt < 3; ++nt) {
    f32x4 acc = {0.f, 0.f, 0.f, 0.f};
    f16x8 b0 = *(const f16x8*)&sPnT[(nt * 16 + l15) * 72 + lg * 8];
    acc = __builtin_amdgcn_mfma_f32_16x16x32_f16(wa0, b0, acc, 0, 0, 0);
    f16x8 b1 = *(const f16x8*)&sPnT[(nt * 16 + l15) * 72 + 32 + lg * 8];
    acc = __builtin_amdgcn_mfma_f32_16x16x32_f16(wa1, b1, acc, 0, 0, 0);
    #pragma unroll
    for (int r = 0; r < 4; ++r) {
      const int grow = wv * 16 + lg * 4 + r;
      if (grow < 90) {
        Rrow[grow * 48 + nt * 16 + l15] = (f16)acc[r];
        cs[nt] += acc[r];
      }
    }
  }
  #pragma unroll
  for (int nt = 0; nt < 3; ++nt) {
    cs[nt] += __shfl_xor(cs[nt], 16, 64);
    cs[nt] += __shfl_xor(cs[nt], 32, 64);
  }
  if (lane < 16) {
    sCol[wv][0][lane] = cs[0];
    sCol[wv][1][lane] = cs[1];
    sCol[wv][2][lane] = cs[2];
  }
  __syncthreads();
  if (tid < 48) {
    const int nt = tid >> 4, c = tid & 15;
    float s = 0.f;
    #pragma unroll
    for (int w = 0; w < 6; ++w) s += sCol[w][nt][c];
    nmmean[((size_t)br * 1024 + b) * 48 + tid] = s * (1.f / 90.f);
  }
}

// ---------------- Kernel B: graph-level tiny MLPs + soft-protos ----------------
__global__ __launch_bounds__(256) void graph_kernel(
    const float* __restrict__ nmmean,
    const float* __restrict__ Wg, const float* __restrict__ bg,
    const float* __restrict__ Pg,
    const float* __restrict__ Wg1, const float* __restrict__ bg1,
    const float* __restrict__ Wg2, const float* __restrict__ bg2,
    const float* __restrict__ Pc,
    f16* __restrict__ R)
{
  __shared__ float sE[4][64];
  __shared__ float sT[4][64];
  const int tid = threadIdx.x;
  const int wid = tid >> 6, lane = tid & 63;
  const int idx = blockIdx.x * 4 + wid;
  const int br = idx >> 10, b = idx & 1023;
  const float* mrow = nmmean + (size_t)idx * 48;
  f16* Rrow = R + (size_t)b * 8736;

  if (lane < 32) {
    float e = bg[lane];
    #pragma unroll
    for (int k = 0; k < 48; ++k) e = fmaf(mrow[k], Wg[k * 32 + lane], e);
    sE[wid][lane] = e;
  }
  __syncthreads();
  if (lane < 32) {
    float s = 0.f;
    #pragma unroll
    for (int j = 0; j < 32; ++j) { float pv = Pg[lane * 32 + j]; s += pv * (2.f * sE[wid][j] - pv); }
    float m = s;
    for (int d = 16; d >= 1; d >>= 1) m = fmaxf(m, __shfl_xor(m, d, 64));
    float ex = __expf(s - m);
    float sum = ex;
    for (int d = 16; d >= 1; d >>= 1) sum += __shfl_xor(sum, d, 64);
    sT[wid][lane] = ex / sum;
  }
  __syncthreads();
  if (lane < 32) {
    float g = 0.f;
    #pragma unroll
    for (int p = 0; p < 32; ++p) g = fmaf(sT[wid][p], Pg[p * 32 + lane], g);
    Rrow[8640 + br * 32 + lane] = (f16)g;
    sE[wid][lane] = g;
  }
  __syncthreads();
  if (lane < 32) {
    float h = bg1[lane];
    #pragma unroll
    for (int k = 0; k < 32; ++k) h = fmaf(sE[wid][k], Wg1[k * 32 + lane], h);
    sT[wid][lane] = fmaxf(h, 0.f);
  }
  __syncthreads();
  if (lane < 16) {
    float c = bg2[lane];
    #pragma unroll
    for (int k = 0; k < 32; ++k) c = fmaf(sT[wid][k], Wg2[k * 16 + lane], c);
    sE[wid][lane] = c;
  }
  __syncthreads();
  if (lane < 16) {
    float s = 0.f;
    #pragma unroll
    for (int j = 0; j < 16; ++j) { float pv = Pc[lane * 16 + j]; s += pv * (2.f * sE[wid][j] - pv); }
    float m = s;
    for (int d = 8; d >= 1; d >>= 1) m = fmaxf(m, __shfl_xor(m, d, 64));
    float ex = __expf(s - m);
    float sum = ex;
    for (int d = 8; d >= 1; d >>= 1) sum += __shfl_xor(sum, d, 64);
    sT[wid][lane] = ex / sum;
  }
  __syncthreads();
  if (lane < 16) {
    float c = 0.f;
    #pragma unroll
    for (int p = 0; p < 16; ++p) c = fmaf(sT[wid][p], Pc[p * 16 + lane], c);
    Rrow[8704 + br * 16 + lane] = (f16)c;
  }
}

// ---------------- split-K f16-MFMA GEMM with register prefetch ----------------
__global__ __launch_bounds__(256) void gemm1_kernel(
    const f16* __restrict__ R, const f16* __restrict__ Wc1T,
    float* __restrict__ part, int KS)
{
  __shared__ __align__(16) f16 sA[128 * 40];
  __shared__ __align__(16) f16 sB[64 * 40];
  const int tid = threadIdx.x;
  const int lane = tid & 63, wv = tid >> 6;
  const int l15 = lane & 15, lg = lane >> 4;
  const int wm = wv >> 1, wn = wv & 1;
  const int bm = blockIdx.x * 128, bnc = blockIdx.y * 64, z = blockIdx.z;
  const int base = 273 / KS, rem = 273 - base * KS;
  const int t0 = z * base + (z < rem ? z : rem);
  const int nt_ = base + (z < rem ? 1 : 0);
  const int kbeg = t0 * 32, kend = (t0 + nt_) * 32;

  const int ar = tid >> 1, ah = (tid & 1) * 16;
  const int bc = tid >> 2, bh = (tid & 3) * 8;

  f32x4 acc[4][2];
  #pragma unroll
  for (int mt = 0; mt < 4; ++mt)
    #pragma unroll
    for (int nt = 0; nt < 2; ++nt) acc[mt][nt] = (f32x4){0.f, 0.f, 0.f, 0.f};

  // prefetch first tile into registers
  f16x8 v0 = *(const f16x8*)&R[(size_t)(bm + ar) * 8736 + kbeg + ah];
  f16x8 v1 = *(const f16x8*)&R[(size_t)(bm + ar) * 8736 + kbeg + ah + 8];
  f16x8 w0 = *(const f16x8*)&Wc1T[(size_t)(bnc + bc) * 8736 + kbeg + bh];

  for (int kk = kbeg; kk < kend; kk += 32) {
    *(f16x8*)&sA[ar * 40 + ah] = v0;
    *(f16x8*)&sA[ar * 40 + ah + 8] = v1;
    *(f16x8*)&sB[bc * 40 + bh] = w0;
    __syncthreads();
    if (kk + 32 < kend) {   // issue next-tile loads; latency hides under MFMAs
      v0 = *(const f16x8*)&R[(size_t)(bm + ar) * 8736 + kk + 32 + ah];
      v1 = *(const f16x8*)&R[(size_t)(bm + ar) * 8736 + kk + 32 + ah + 8];
      w0 = *(const f16x8*)&Wc1T[(size_t)(bnc + bc) * 8736 + kk + 32 + bh];
    }
    #pragma unroll
    for (int mt = 0; mt < 4; ++mt) {
      f16x8 a = *(const f16x8*)&sA[(wm * 64 + mt * 16 + l15) * 40 + lg * 8];
      #pragma unroll
      for (int nt = 0; nt < 2; ++nt) {
        f16x8 bb = *(const f16x8*)&sB[(wn * 32 + nt * 16 + l15) * 40 + lg * 8];
        acc[mt][nt] = __builtin_amdgcn_mfma_f32_16x16x32_f16(a, bb, acc[mt][nt], 0, 0, 0);
      }
    }
    __syncthreads();
  }
  float* pz = part + (size_t)z * 262144;
  #pragma unroll
  for (int mt = 0; mt < 4; ++mt)
    #pragma unroll
    for (int nt = 0; nt < 2; ++nt)
      #pragma unroll
      for (int r = 0; r < 4; ++r)
        pz[(size_t)(bm + wm * 64 + mt * 16 + lg * 4 + r) * 256 +
           bnc + wn * 32 + nt * 16 + l15] = acc[mt][nt][r];
}

// ---------------- reduce K-partials + relu + [256->3] head ----------------
__global__ __launch_bounds__(256) void head_kernel(
    const float* __restrict__ part, const float* __restrict__ bc1,
    const float* __restrict__ Wc2, const float* __restrict__ bc2,
    float* __restrict__ out, int KS)
{
  __shared__ float red[3][4];
  const int b = blockIdx.x, t = threadIdx.x;
  float s0 = 0.f, s1 = 0.f, s2 = 0.f, s3 = 0.f;   // independent chains
  int z = 0;
  for (; z + 4 <= KS; z += 4) {
    s0 += part[(size_t)(z + 0) * 262144 + (size_t)b * 256 + t];
    s1 += part[(size_t)(z + 1) * 262144 + (size_t)b * 256 + t];
    s2 += part[(size_t)(z + 2) * 262144 + (size_t)b * 256 + t];
    s3 += part[(size_t)(z + 3) * 262144 + (size_t)b * 256 + t];
  }
  for (; z < KS; ++z) s0 += part[(size_t)z * 262144 + (size_t)b * 256 + t];
  float acc = bc1[t] + ((s0 + s1) + (s2 + s3));
  float h = fmaxf(acc, 0.f);
  float p0 = h * Wc2[t * 3 + 0];
  float p1 = h * Wc2[t * 3 + 1];
  float p2 = h * Wc2[t * 3 + 2];
  for (int d = 32; d >= 1; d >>= 1) {
    p0 += __shfl_xor(p0, d, 64);
    p1 += __shfl_xor(p1, d, 64);
    p2 += __shfl_xor(p2, d, 64);
  }
  const int wid = t >> 6, lane = t & 63;
  if (lane == 0) { red[0][wid] = p0; red[1][wid] = p1; red[2][wid] = p2; }
  __syncthreads();
  if (t < 3) {
    out[(size_t)b * 3 + t] = red[t][0] + red[t][1] + red[t][2] + red[t][3] + bc2[t];
  }
}

extern "C" void kernel_launch(void* const* d_in, const int* in_sizes, int n_in,
                              void* d_out, int out_size, void* d_ws, size_t ws_size,
                              hipStream_t stream) {
  const float* fcn     = (const float*)d_in[0];
  const float* scn     = (const float*)d_in[1];
  const float* W_node  = (const float*)d_in[2];
  const float* b_node  = (const float*)d_in[3];
  const float* P_node  = (const float*)d_in[4];
  const float* W_graph = (const float*)d_in[5];
  const float* b_graph = (const float*)d_in[6];
  const float* P_graph = (const float*)d_in[7];
  const float* Wg1     = (const float*)d_in[8];
  const float* bg1     = (const float*)d_in[9];
  const float* Wg2     = (const float*)d_in[10];
  const float* bg2     = (const float*)d_in[11];
  const float* P_cls   = (const float*)d_in[12];
  const float* Wc1     = (const float*)d_in[13];
  const float* bc1     = (const float*)d_in[14];
  const float* Wc2     = (const float*)d_in[15];
  const float* bc2     = (const float*)d_in[16];
  float* out = (float*)d_out;

  char* ws = (char*)d_ws;
  f16*   R16    = (f16*)ws;                        // 17,891,328 B
  f16*   Wc1T   = (f16*)(ws + 17891328);           //  4,472,832 B
  f16*   wf     = (f16*)(ws + 22364160);           //     24,064 B
  float* qbuf   = (float*)(ws + 22388224);         //        256 B
  float* nmmean = (float*)(ws + 22388480);         //    393,216 B
  float* part   = (float*)(ws + 22781696);         // KS * 1,048,576 B

  size_t avail = ws_size > 22781696u ? ws_size - 22781696u : 0;
  int KS = (int)(avail / 1048576u);
  if (KS > 16) KS = 16;
  if (KS < 1) KS = 1;

  prep_kernel<<<48, 256, 0, stream>>>(W_node, P_node, wf, qbuf);
  wc1t_kernel<<<dim3(273, 8), 256, 0, stream>>>(Wc1, Wc1T);
  node_kernel<<<dim3(1024, 2), 384, 0, stream>>>(fcn, scn, b_node, wf, qbuf,
                                                 R16, nmmean);
  graph_kernel<<<512, 256, 0, stream>>>(nmmean, W_graph, b_graph, P_graph,
                                        Wg1, bg1, Wg2, bg2, P_cls, R16);
  gemm1_kernel<<<dim3(8, 4, KS), 256, 0, stream>>>(R16, Wc1T, part, KS);
  head_kernel<<<1024, 256, 0, stream>>>(part, bc1, Wc2, bc2, out, KS);
}